// Round 1
// 358.059 us; speedup vs baseline: 1.0261x; 1.0261x over previous
//
#include <hip/hip_runtime.h>
#include <stdint.h>

typedef __bf16 bf16;
typedef bf16 bf16x4 __attribute__((ext_vector_type(4)));
typedef bf16 bf16x8 __attribute__((ext_vector_type(8)));
typedef float f32x4 __attribute__((ext_vector_type(4)));

#define N_NODES 131072
#define D_IN    128
#define KEXP    1024
#define H_DIM   512
#define NGRP    4
#define NPG     32768   // N_NODES / NGRP
#define F_SEG   8192
#define G_SEG   32
#define C_OUT   16

// async global->LDS DMA, 16B per lane; LDS dest = wave-uniform base + lane*16
typedef const __attribute__((address_space(1))) void* gas_t;
typedef __attribute__((address_space(3))) void* las_t;
__device__ __forceinline__ void cp16_async(const bf16* g, bf16* l) {
    __builtin_amdgcn_global_load_lds((gas_t)g, (las_t)l, 16, 0, 0);
}

// ---------------------------------------------------------------------------
// One-time weight cast + swizzle into MFMA-fragment order (16x16x32 bf16).
// B-frag: lane (quad=lane>>4, ln=lane&15) holds B[k=quad*8+j][n=ln].
// (The same physical layout serves as A-frag with rows=ln, k=quad*8+j.)
//
// W1F[g][kc(32)][f=ks*2+kt (8)][lane(64)][j(8)]
//     = W1[g][d = ks*32 + quad*8 + j][k' = kc*32 + kt*16 + ln]
// W2F[g][n0t2(2)][kc(32)][f(16)][lane][j]
//     = W2[g][k = kc*32 + quad*8 + j][n = n0t2*256 + f*16 + ln]
// ---------------------------------------------------------------------------
__global__ void convert_weights(const float* __restrict__ W1,
                                const float* __restrict__ W2,
                                bf16* __restrict__ W1F,
                                bf16* __restrict__ W2F)
{
    int t = blockIdx.x * 256 + threadIdx.x;
    if (t < 65536) {
        int slot = t & 63, f = (t >> 6) & 7, kc = (t >> 9) & 31, g = t >> 14;
        int ks = f >> 1, kt = f & 1, quad = slot >> 4, ln = slot & 15;
        int k = kc * 32 + kt * 16 + ln;
        const float* src = W1 + ((size_t)(g * 128 + ks * 32 + quad * 8)) * 1024 + k;
        bf16x8 v;
        #pragma unroll
        for (int j = 0; j < 8; ++j) v[j] = (bf16)src[(size_t)j * 1024];
        *(bf16x8*)(W1F + (size_t)t * 8) = v;
    } else {
        int u = t - 65536;
        if (u < 262144) {
            int slot = u & 63, f = (u >> 6) & 15, kc = (u >> 10) & 31;
            int n0t2 = (u >> 15) & 1, g = u >> 16;
            int quad = slot >> 4, ln = slot & 15;
            int k = kc * 32 + quad * 8;
            int n = n0t2 * 256 + f * 16 + ln;
            const float* src = W2 + ((size_t)(g * 1024 + k)) * 512 + n;
            bf16x8 v;
            #pragma unroll
            for (int j = 0; j < 8; ++j) v[j] = (bf16)src[(size_t)j * 512];
            *(bf16x8*)(W2F + (size_t)u * 8) = v;
        }
    }
}

// ---------------------------------------------------------------------------
// Fused gather + GEMM1(relu) + GEMM2 + scatter. 256 threads (4 waves).
// Round-9: counted-vmcnt pipeline (T3/T4). The R8 structure was at the
// 2-barrier/full-drain ceiling (855 TF eff, MfmaUtil 36% == m97's 37%).
// Changes:
//  * raw s_barrier + counted s_waitcnt, NEVER vmcnt(0) in the loop; both
//    W1(kc+1) and W2(kc+1) are issued at the top of kc -> full-kc flight.
//  * sW2 TRIPLE-buffered: the kc+1 issue targets a buffer last read at
//    stage2(kc-2), which every wave finished before barrier B2(kc-1) --
//    with 2 buffers the issue would race other waves still in stage2(kc-1).
//  * sW1 dbuf WAR safe: target (kc+1)&1 last read at stage1(kc-1), done by
//    all waves before B3(kc-1), which we passed. sH single-buffer safe:
//    stage1(kc) writes begin after B2(kc), by which all waves finished
//    stage2(kc-1) reads. All asm waits carry "memory" so LDS ops can't
//    drift across the fences (only reg-only MFMA may, which is harmless).
//  * bias b1 staged to LDS once (sB1): vmcnt retires IN ORDER, so any
//    in-loop global load consumed in stage1 would force-drain the new
//    prefetches and collapse the pipeline.
//  * s_setprio(1) around both MFMA clusters (T5: pays once phases give
//    waves role-split).
// Per-wave in-loop vmem = exactly 6 DMAs (2xW1 then 4xW2):
//   top of kc: outstanding [W1(kc)2, W2(kc)4] + issue 6 new = 12
//   vmcnt(10) -> drains W1(kc) (stage1 needs it), 10 left in flight
//   vmcnt(6)+lgkmcnt(0) before B3 -> drains W2(kc), publishes sH
// LDS: sW1 2x8K + sW2 3x16K + sH 8K + sB1 4K = 76 KB -> 2 blocks/CU.
// ---------------------------------------------------------------------------
__global__ __launch_bounds__(256, 2)
void mlp_kernel(const float* __restrict__ x,
                const int*   __restrict__ gidx,
                const bf16*  __restrict__ W1F,
                const float* __restrict__ b1,
                const bf16*  __restrict__ W2F,
                const float* __restrict__ b2,
                bf16*        __restrict__ NF)
{
    __shared__ __align__(16) bf16 sW1[2][4096]; // [f=ks*2+kt (8)][lane][8]
    __shared__ __align__(16) bf16 sW2[3][8192]; // [f (16)][lane][8]
    __shared__ __align__(16) bf16 sH[4096];     // A-frag order [fm (8)][lane][8]
    __shared__ __align__(16) float sB1[1024];   // this group's b1 row

    const int tid  = threadIdx.x;
    const int bid  = blockIdx.x;
    const int g    = bid >> 9;
    const int rem  = bid & 511;
    const int m0   = (rem >> 1) * 128;
    const int n0t2 = rem & 1;

    const int wave = tid >> 6;
    const int lane = tid & 63;
    const int quad = lane >> 4;
    const int ln   = lane & 15;
    const int mg   = wave >> 1;   // stage-2 row group (64 rows)
    const int ng   = wave & 1;    // stage-2 col group (128 cols)

    const int*  gI  = gidx + g * NPG + m0;
    const bf16* W1g = W1F + (size_t)g * 131072;                   // [kc][4096]
    const bf16* W2g = W2F + (size_t)(g * 2 + n0t2) * 262144;      // [kc][8192]

    // ---- gather x B-frags straight into registers (reused all 32 kc) ----
    // frag i (mt=i>>2, ks=i&3): lane holds x[row=wave*32+mt*16+ln][ks*32+quad*8 ..+8)
    bf16x8 xf[8];
    #pragma unroll
    for (int i = 0; i < 8; ++i) {
        int row  = wave * 32 + (i >> 2) * 16 + ln;
        int node = gI[row];
        const float* src = x + (size_t)node * D_IN + (i & 3) * 32 + quad * 8;
        float4 a = *(const float4*)src;
        float4 b = *(const float4*)(src + 4);
        bf16x8 v;
        v[0] = (bf16)a.x; v[1] = (bf16)a.y; v[2] = (bf16)a.z; v[3] = (bf16)a.w;
        v[4] = (bf16)b.x; v[5] = (bf16)b.y; v[6] = (bf16)b.z; v[7] = (bf16)b.w;
        xf[i] = v;
    }

    // stage whole bias row to LDS (keeps the K-loop free of global loads)
    *(float4*)(sB1 + tid * 4) = *(const float4*)(b1 + g * KEXP + tid * 4);

    f32x4 acc2[4][8];   // [mt: rows mg*64+mt*16][nt: cols ng*128+nt*16]
    #pragma unroll
    for (int a = 0; a < 4; ++a)
        #pragma unroll
        for (int b = 0; b < 8; ++b)
            acc2[a][b] = (f32x4){0.f, 0.f, 0.f, 0.f};

    // full-drain barrier ONCE: publishes sB1, prologue gathers already consumed
    __syncthreads();

    // ---- preloop: chunk 0 DMA, W1 FIRST then W2 (vmcnt counts rely on it) ----
    #pragma unroll
    for (int r = 0; r < 2; ++r) {
        int c = r * 4 + wave;
        cp16_async(W1g + c * 512 + lane * 8, sW1[0] + c * 512);
    }
    #pragma unroll
    for (int r = 0; r < 4; ++r) {
        int c = r * 4 + wave;
        cp16_async(W2g + c * 512 + lane * 8, sW2[0] + c * 512);
    }

    int w2c = 0;   // sW2 buffer holding chunk kc (== kc % 3)
    #pragma unroll 1
    for (int kc = 0; kc < 32; ++kc) {
        const int w2n = (w2c == 2) ? 0 : (w2c + 1);
        const int nkc = (kc + 1) & 31;     // wrap at kc=31: harmless refetch,
                                           // keeps vmcnt counts uniform

        // ---- issue next chunk: W1(kc+1) then W2(kc+1) ----
        {
            const bf16* w1src = W1g + (size_t)nkc * 4096;
            bf16* d1 = sW1[(kc + 1) & 1];
            #pragma unroll
            for (int r = 0; r < 2; ++r) {
                int c = r * 4 + wave;
                cp16_async(w1src + c * 512 + lane * 8, d1 + c * 512);
            }
            const bf16* w2src = W2g + (size_t)nkc * 8192;
            bf16* d2 = sW2[w2n];
            #pragma unroll
            for (int r = 0; r < 4; ++r) {
                int c = r * 4 + wave;
                cp16_async(w2src + c * 512 + lane * 8, d2 + c * 512);
            }
        }

        // W1(kc) landed (own 2 oldest); 4x W2(kc) + 6 new stay in flight
        asm volatile("s_waitcnt vmcnt(10)" ::: "memory");
        __builtin_amdgcn_s_barrier();   // B2: everyone's W1(kc) landed;
                                        // all waves done stage2(kc-1) -> sH WAR safe

        // ---- stage 1 (swapped): D[k'][m] = W1c^T-tile x x-tile ----
        // acc1[kt][mt]: rows k' = kt*16+quad*4+reg, cols m = mt*16+ln
        const bf16* w1buf = sW1[kc & 1];
        f32x4 acc1[2][2];
        #pragma unroll
        for (int a = 0; a < 2; ++a)
            #pragma unroll
            for (int b = 0; b < 2; ++b)
                acc1[a][b] = (f32x4){0.f, 0.f, 0.f, 0.f};

        __builtin_amdgcn_s_setprio(1);
        #pragma unroll
        for (int ks = 0; ks < 4; ++ks) {
            #pragma unroll
            for (int kt = 0; kt < 2; ++kt) {
                bf16x8 w1f = *(const bf16x8*)(w1buf + ((ks * 2 + kt) * 64 + lane) * 8);
                #pragma unroll
                for (int mt = 0; mt < 2; ++mt)
                    acc1[kt][mt] = __builtin_amdgcn_mfma_f32_16x16x32_bf16(
                        w1f, xf[mt * 4 + ks], acc1[kt][mt], 0, 0, 0);
            }
        }
        __builtin_amdgcn_s_setprio(0);

        // bias+relu -> sH via b64 stores (4 contiguous k' per lane at fixed m)
        // value: h[m = wave*32+mt*16+ln][k' = kt*16+quad*4+reg]
        // dest A-frag elem: fm = wave*2+mt, qa = kt*2+(quad>>1), j = (quad&1)*4+reg
        #pragma unroll
        for (int kt = 0; kt < 2; ++kt) {
            float4 bv = *(const float4*)(sB1 + kc * 32 + kt * 16 + quad * 4);
            float bvr[4] = {bv.x, bv.y, bv.z, bv.w};
            int qa = kt * 2 + (quad >> 1);
            int j0 = (quad & 1) * 4;
            #pragma unroll
            for (int mt = 0; mt < 2; ++mt) {
                int fm = wave * 2 + mt;
                bf16x4 pk;
                #pragma unroll
                for (int reg = 0; reg < 4; ++reg)
                    pk[reg] = (bf16)fmaxf(acc1[kt][mt][reg] + bvr[reg], 0.f);
                *(bf16x4*)(sH + (fm * 64 + qa * 16 + ln) * 8 + j0) = pk;
            }
        }

        // W2(kc) landed + sH writes drained; 6 next-chunk DMAs stay in flight
        asm volatile("s_waitcnt vmcnt(6) lgkmcnt(0)" ::: "memory");
        __builtin_amdgcn_s_barrier();   // B3: sH + sW2[w2c] visible to all

        // ---- stage 2: og[mg rows 64][ng cols 128] += h @ W2c ----
        const bf16* w2buf = sW2[w2c];
        bf16x8 bb[8];
        #pragma unroll
        for (int nt = 0; nt < 8; ++nt)
            bb[nt] = *(const bf16x8*)(w2buf + ((ng * 8 + nt) * 64 + lane) * 8);
        __builtin_amdgcn_s_setprio(1);
        #pragma unroll
        for (int mt = 0; mt < 4; ++mt) {
            bf16x8 a2 = *(const bf16x8*)(sH + ((mg * 4 + mt) * 64 + lane) * 8);
            #pragma unroll
            for (int nt = 0; nt < 8; ++nt)
                acc2[mt][nt] = __builtin_amdgcn_mfma_f32_16x16x32_bf16(
                    a2, bb[nt], acc2[mt][nt], 0, 0, 0);
        }
        __builtin_amdgcn_s_setprio(0);

        w2c = w2n;
    }

    // ---- epilogue: + b2, scatter rows to NF[node][H] as bf16 ----
    const float* b2g = b2 + g * H_DIM + n0t2 * 256 + ng * 128;
    float b2v[8];
    #pragma unroll
    for (int nt = 0; nt < 8; ++nt) b2v[nt] = b2g[nt * 16 + ln];

    #pragma unroll
    for (int mt = 0; mt < 4; ++mt)
        #pragma unroll
        for (int reg = 0; reg < 4; ++reg) {
            int row  = mg * 64 + mt * 16 + quad * 4 + reg;
            int node = gI[row];
            bf16* dst = NF + (size_t)node * H_DIM + n0t2 * 256 + ng * 128;
            #pragma unroll
            for (int nt = 0; nt < 8; ++nt)
                dst[nt * 16 + ln] = (bf16)(acc2[mt][nt][reg] + b2v[nt]);
        }
}

// ---------------------------------------------------------------------------
// segment_max over 16 consecutive nodes per fine cluster (sorted arange ids).
// Thread handles one (f, 8-channel group); uint4 loads (16 B/lane).
// ---------------------------------------------------------------------------
__global__ void pool_kernel(const bf16* __restrict__ NF, float* __restrict__ EMB)
{
    int t  = blockIdx.x * 256 + threadIdx.x;    // 524288 total
    int f  = t >> 6;
    int c8 = (t & 63) * 8;
    const uint4* src = (const uint4*)(NF + (size_t)f * 16 * 512 + c8);
    float m[8];
    #pragma unroll
    for (int i = 0; i < 8; ++i) m[i] = -INFINITY;
    #pragma unroll
    for (int r = 0; r < 16; ++r) {
        uint4 v = src[(size_t)r * 64];
        uint32_t w[4] = {v.x, v.y, v.z, v.w};
        #pragma unroll
        for (int i = 0; i < 4; ++i) {
            m[2*i]   = fmaxf(m[2*i],   __uint_as_float(w[i] << 16));
            m[2*i+1] = fmaxf(m[2*i+1], __uint_as_float(w[i] & 0xffff0000u));
        }
    }
    float* dst = EMB + (size_t)f * 512 + c8;
    *(float4*)dst       = make_float4(m[0], m[1], m[2], m[3]);
    *(float4*)(dst + 4) = make_float4(m[4], m[5], m[6], m[7]);
}

// ---------------------------------------------------------------------------
// Per (coarse group, channel) mean / rsqrt(var+eps) over 256 fine rows.
// ---------------------------------------------------------------------------
__global__ void stats_kernel(const float* __restrict__ EMB,
                             float* __restrict__ MEAN,
                             float* __restrict__ RSIG)
{
    int gc = blockIdx.x;
    int ch = blockIdx.y * 128 + threadIdx.x;
    const float* p = EMB + (size_t)gc * 256 * 512 + ch;
    float s = 0.f, ss = 0.f;
    #pragma unroll 4
    for (int r = 0; r < 256; ++r) {
        float v = p[(size_t)r * 512];
        s += v; ss += v * v;
    }
    float mean = s * (1.f / 256.f);
    float var  = ss * (1.f / 256.f) - mean * mean;
    MEAN[gc * 512 + ch] = mean;
    RSIG[gc * 512 + ch] = rsqrtf(var + 1e-5f);
}

// ---------------------------------------------------------------------------
// logits[f][c] = b_out[c] + sum_h (emb[f][h]-mean)*rsig * w_out[h][c]
// ---------------------------------------------------------------------------
__global__ __launch_bounds__(256)
void classifier_kernel(const float* __restrict__ EMB,
                       const float* __restrict__ MEAN,
                       const float* __restrict__ RSIG,
                       const float* __restrict__ w_out,
                       const float* __restrict__ b_out,
                       float* __restrict__ out)
{
    __shared__ float sW[512 * 16];
    __shared__ float sE[16 * 513];   // +1 pad breaks 4-way bank conflict
    int t  = threadIdx.x;
    int f0 = blockIdx.x * 16;
    int gc = f0 >> 8;

    #pragma unroll
    for (int it = 0; it < 8; ++it) {
        int i = (it * 256 + t) * 4;
        *(float4*)(sW + i) = *(const float4*)(w_out + i);
    }
    #pragma unroll
    for (int it = 0; it < 32; ++it) {
        int i  = it * 256 + t;
        int fr = i >> 9;
        int h  = i & 511;
        float v = EMB[(size_t)(f0 + fr) * 512 + h];
        sE[fr * 513 + h] = (v - MEAN[gc * 512 + h]) * RSIG[gc * 512 + h];
    }
    __syncthreads();

    int fr = t >> 4;
    int c  = t & 15;
    float acc = b_out[c];
    #pragma unroll 8
    for (int h = 0; h < 512; ++h)
        acc += sE[fr * 513 + h] * sW[h * 16 + c];
    out[(size_t)(f0 + fr) * 16 + c] = acc;
}

// ---------------------------------------------------------------------------
// Workspace layout (~156.4 MB):
//   W1F 1 MB | W2F 4 MB | NF 134 MB | EMB 16 MB | MEAN 64K | RSIG 64K
// ---------------------------------------------------------------------------
extern "C" void kernel_launch(void* const* d_in, const int* in_sizes, int n_in,
                              void* d_out, int out_size, void* d_ws, size_t ws_size,
                              hipStream_t stream)
{
    const float* x     = (const float*)d_in[0];
    const int*   gidx  = (const int*)d_in[1];
    const float* W1    = (const float*)d_in[4];
    const float* b1    = (const float*)d_in[5];
    const float* W2    = (const float*)d_in[6];
    const float* b2    = (const float*)d_in[7];
    const float* w_out = (const float*)d_in[8];
    const float* b_out = (const float*)d_in[9];
    float* out = (float*)d_out;

    char* w = (char*)d_ws;
    bf16* W1F = (bf16*)w;  w += (size_t)NGRP * KEXP * D_IN * 2;
    bf16* W2F = (bf16*)w;  w += (size_t)NGRP * H_DIM * KEXP * 2;
    bf16* NF  = (bf16*)w;  w += (size_t)N_NODES * H_DIM * 2;
    float* EMB  = (float*)w; w += (size_t)F_SEG * H_DIM * 4;
    float* MEAN = (float*)w; w += (size_t)G_SEG * H_DIM * 4;
    float* RSIG = (float*)w; w += (size_t)G_SEG * H_DIM * 4;

    convert_weights<<<1280, 256, 0, stream>>>(W1, W2, W1F, W2F);
    mlp_kernel<<<2048, 256, 0, stream>>>(x, gidx, W1F, b1, W2F, b2, NF);
    pool_kernel<<<2048, 256, 0, stream>>>(NF, EMB);
    stats_kernel<<<dim3(32, 4), 128, 0, stream>>>(EMB, MEAN, RSIG);
    classifier_kernel<<<512, 256, 0, stream>>>(EMB, MEAN, RSIG, w_out, b_out, out);
}